// Round 3
// baseline (142.620 us; speedup 1.0000x reference)
//
#include <hip/hip_runtime.h>

// GNN layer: out = segment_sum(nf[src], dst) @ W.T + b
// N=50000, E=800000, D=128.
// R16: source-locality quadrant passes. R15 post-mortem: VGPR_Count=32 shows
// the compiler sank the prefetch (pipeline defeated); VALU/ILP changes bounce
// off because the kernel is L2-MISS-LATENCY x MSHR bound: FETCH 79.8MB for
// 16MB unique data = per-XCD 4MB L2 thrashed by the 12.8MB nfh gather set
// (~67% miss to IC @ ~700cyc; ~64-128 outstanding lines/CU caps gather at
// ~11-23 B/cyc/CU ~= the observed 48us). Fix: partition each node's edges by
// SOURCE QUADRANT (4 bins x 16384 sources ~= 4MB of nfh) and walk Phase B
// quadrant-major. All co-resident blocks on an XCD then gather from the same
// ~4MB window simultaneously -> gather becomes mostly L2-hit. A2/A3 build a
// 512-bin (node x quad) local CSR; accumulators persist across quads
// (2 nodes x 8 dims x f32 = 32 VGPR). Producer unchanged.

constexpr int NN = 50000;
constexpr int NE = 800000;
constexpr int D  = 128;

constexpr int BS   = 128;                      // nodes per bucket
constexpr int NB   = (NN + BS - 1) / BS;       // 391 buckets
constexpr int EPB  = 4096;                     // edges per producer block
constexpr int NSB  = (NE + EPB - 1) / EPB;     // 196 producer blocks
constexpr int CAP  = 4096;                     // per-bucket edge cap

constexpr int NQ   = 4;                        // source quadrants (16384 each)
constexpr int BINS = BS * NQ;                  // 512 local CSR bins

constexpr int AROWU = 136;                     // tile row stride (ushorts)

typedef __attribute__((ext_vector_type(8))) short bf16x8;
typedef __attribute__((ext_vector_type(4))) float f32x4;
typedef __attribute__((ext_vector_type(2))) float f32x2;

__device__ inline unsigned short f2bf(float f) {           // RNE
    unsigned u = __float_as_uint(f);
    return (unsigned short)((u + 0x7fffu + ((u >> 16) & 1u)) >> 16);
}
__device__ inline float bflo(unsigned v) { return __uint_as_float(v << 16); }
__device__ inline float bfhi(unsigned v) { return __uint_as_float(v & 0xffff0000u); }

__device__ inline int wscan(int v) {           // wave-inclusive scan (64)
    #pragma unroll
    for (int o = 1; o < 64; o <<= 1) {
        int u = __shfl_up(v, o);
        if ((int)(threadIdx.x & 63) >= o) v += u;
    }
    return v;
}

__device__ inline void acc8(f32x2& a0, f32x2& a1, f32x2& a2, f32x2& a3, uint4 v) {
    a0 += (f32x2){bflo(v.x), bfhi(v.x)};
    a1 += (f32x2){bflo(v.y), bfhi(v.y)};
    a2 += (f32x2){bflo(v.z), bfhi(v.z)};
    a3 += (f32x2){bflo(v.w), bfhi(v.w)};
}

// ---- 1. fused prep (bf16 cvt) + bucket-sort partition ---------------------
constexpr int NF4 = NN * D / 4;                           // 1,600,000
constexpr int W4  = D * D / 4;                            // 4,096
constexpr int NBLK_P = (NF4 + W4 + 511) / 512;            // 3134
constexpr int GRID_A = NSB + NBLK_P;

__global__ __launch_bounds__(512) void k_prep_bucket(
    const float* __restrict__ nf, const float* __restrict__ W,
    const int* __restrict__ ei,
    ushort* __restrict__ nfh, ushort* __restrict__ Wh,
    ushort* __restrict__ offs, unsigned* __restrict__ buf)
{
    __shared__ int hist[NB], cur[NB];              // 3128 B
    __shared__ int wsum[8];
    __shared__ unsigned spk[EPB];                  // 16384 B
    const int t = threadIdx.x, lane = t & 63, w = t >> 6;

    if (blockIdx.x < NSB) {
        const int blk = blockIdx.x;
        const int e0  = blk * EPB;
        int cnt = NE - e0; if (cnt > EPB) cnt = EPB;

        for (int i = t; i < NB; i += 512) hist[i] = 0;
        __syncthreads();

        unsigned pk[8];
        #pragma unroll
        for (int j = 0; j < 8; ++j) {
            int idx = j * 512 + t;
            if (idx < cnt) {
                int e = e0 + idx;
                unsigned s = (unsigned)ei[e];
                unsigned d = (unsigned)ei[NE + e];
                pk[j] = (d << 16) | s;             // bucket = pk >> 23
                atomicAdd(&hist[pk[j] >> 23], 1);
            }
        }
        __syncthreads();
        // wave shfl scan over 391 (waves 0..6 carry data, wave 7 zeros)
        int h = (t < NB) ? hist[t] : 0;
        int v = wscan(h);
        if (lane == 63) wsum[w] = v;
        __syncthreads();
        int addv = 0;
        #pragma unroll
        for (int i = 0; i < 8; ++i) addv += (i < w) ? wsum[i] : 0;
        v += addv;
        if (t < NB) {
            int ex = v - h;                        // exclusive base
            cur[t] = ex;
            offs[t * NSB + blk] = (ushort)ex;      // TRANSPOSED: bucket-major
        }
        if (t == 0) offs[NB * NSB + blk] = (ushort)cnt;
        __syncthreads();
        #pragma unroll
        for (int j = 0; j < 8; ++j) {
            int idx = j * 512 + t;
            if (idx < cnt) {
                int l = atomicAdd(&cur[pk[j] >> 23], 1);
                spk[l] = pk[j];
            }
        }
        __syncthreads();
        for (int i = t; i < cnt; i += 512)         // dense coalesced 16KB
            buf[(size_t)blk * EPB + i] = spk[i];
    } else {
        // prep branch: bf16 conversion
        int i = (blockIdx.x - NSB) * 512 + t;
        if (i < NF4) {
            float4 v = ((const float4*)nf)[i];
            ((ushort4*)nfh)[i] = make_ushort4(f2bf(v.x), f2bf(v.y), f2bf(v.z), f2bf(v.w));
        } else if (i < NF4 + W4) {
            int k = i - NF4;
            float4 v = ((const float4*)W)[k];
            ((ushort4*)Wh)[k] = make_ushort4(f2bf(v.x), f2bf(v.y), f2bf(v.z), f2bf(v.w));
        }
    }
}

// ---- 2. fused gather-sort + aggregate + linear ----------------------------
__global__ __launch_bounds__(1024, 8) void k_sort_agg(
    const unsigned* __restrict__ nfh, const unsigned* __restrict__ buf,
    const ushort* __restrict__ offs, const ushort* __restrict__ Wh,
    const float* __restrict__ bias, float* __restrict__ out)
{
    __shared__ ushort srt[CAP];                     // 8192 B
    __shared__ int scnt[256];                       // 1024 B
    __shared__ int sbase[NSB], rbase[NSB];          // 1568 B
    __shared__ int hist[BINS], off[BINS], cur[BINS];// 6144 B (node x quad CSR)
    __shared__ int wred[16];
    __shared__ __align__(16) unsigned tile[BS * AROWU / 2];  // 34816 B
    const int b = blockIdx.x, t = threadIdx.x;
    const int lane = t & 63, w = t >> 6;

    // --- Phase A1: per-producer run bases/counts -> wave shfl scan (1 barrier)
    int my = 0;
    if (t < NSB) {
        int o0 = (int)offs[b * NSB + t];           // coalesced 392B row
        int o1 = (int)offs[(b + 1) * NSB + t];
        rbase[t] = o0;
        my = o1 - o0;
    }
    if (t < BINS) hist[t] = 0;
    int vs = 0;
    if (w < 4) {
        vs = wscan(my);
        if (lane == 63) wred[w] = vs;
    }
    __syncthreads();
    if (w < 4) {
        int addv = 0;
        #pragma unroll
        for (int i = 0; i < 3; ++i) addv += (i < w) ? wred[i] : 0;
        vs += addv;
        scnt[t] = vs;                              // global inclusive
        if (t < NSB) sbase[t] = vs - my;
    }
    __syncthreads();
    int total = scnt[NSB - 1];
    if (total > CAP) total = CAP;                  // defensive

    // --- Phase A2: load pk into REGISTERS + (node x quad) histogram
    unsigned mypk[4];
    int mycnt = 0;
    #pragma unroll
    for (int j = 0; j < 4; ++j) {
        int p = t + j * 1024;
        if (p < total) {
            int lo = 0, hi = NSB - 1;              // min i: scnt[i] > p
            while (lo < hi) {
                int mid = (lo + hi) >> 1;
                if (scnt[mid] > p) hi = mid; else lo = mid + 1;
            }
            unsigned pk = buf[(size_t)lo * EPB + rbase[lo] + (p - sbase[lo])];
            mypk[j] = pk;
            int bin = ((pk >> 16) & (BS - 1)) * NQ + ((pk & 0xffffu) >> 14);
            atomicAdd(&hist[bin], 1);
            mycnt = j + 1;
        }
    }
    __syncthreads();

    // --- Phase A3: 512-bin wave-scan (2 barriers) + scatter (local CSR)
    int hv = (t < BINS) ? hist[t] : 0;
    int nv = 0;
    if (w < 8) {
        nv = wscan(hv);
        if (lane == 63) wred[8 + w] = nv;
    }
    __syncthreads();
    if (t < BINS) {
        int addv = 0;
        #pragma unroll
        for (int i = 0; i < 7; ++i) addv += (i < w) ? wred[8 + i] : 0;
        int ex = nv + addv - hv;
        off[t] = ex; cur[t] = ex;
    }
    __syncthreads();
    #pragma unroll
    for (int j = 0; j < 4; ++j) {
        if (j < mycnt) {
            unsigned pk = mypk[j];
            int bin = ((pk >> 16) & (BS - 1)) * NQ + ((pk & 0xffffu) >> 14);
            int p = atomicAdd(&cur[bin], 1);
            srt[p] = (ushort)(pk & 0xffffu);
        }
    }
    __syncthreads();

    // --- Phase B: QUADRANT-MAJOR gather. All co-resident blocks walk the
    // same ~4MB source window of nfh at once -> L2-hit gather.
    // quarter qq owns nodes {w*8+qq, w*8+4+qq}; accumulators live across quads.
    const int qq = lane >> 4;
    const int sl = lane & 15;
    const uint4* nfv = (const uint4*)nfh;          // row = idx*16 uint4s

    f32x2 A0[4] = {{0.f,0.f},{0.f,0.f},{0.f,0.f},{0.f,0.f}};   // node i=0
    f32x2 A1[4] = {{0.f,0.f},{0.f,0.f},{0.f,0.f},{0.f,0.f}};   // node i=1

    #pragma unroll 1
    for (int q = 0; q < NQ; ++q) {
        #pragma unroll
        for (int i = 0; i < 2; ++i) {
            const int n = w * 8 + i * 4 + qq;
            const int bin = n * NQ + q;
            const int beg = off[bin], cnt = hist[bin];
            f32x2& a0 = i ? A1[0] : A0[0];
            f32x2& a1 = i ? A1[1] : A0[1];
            f32x2& a2 = i ? A1[2] : A0[2];
            f32x2& a3 = i ? A1[3] : A0[3];
            const int nfull = cnt & ~3;
            if (nfull > 0) {
                uint4 v0 = nfv[(size_t)srt[beg + 0] * 16 + sl];
                uint4 v1 = nfv[(size_t)srt[beg + 1] * 16 + sl];
                uint4 v2 = nfv[(size_t)srt[beg + 2] * 16 + sl];
                uint4 v3 = nfv[(size_t)srt[beg + 3] * 16 + sl];
                for (int p = 4; p < nfull; p += 4) {
                    uint4 u0 = nfv[(size_t)srt[beg + p + 0] * 16 + sl];
                    uint4 u1 = nfv[(size_t)srt[beg + p + 1] * 16 + sl];
                    uint4 u2 = nfv[(size_t)srt[beg + p + 2] * 16 + sl];
                    uint4 u3 = nfv[(size_t)srt[beg + p + 3] * 16 + sl];
                    acc8(a0, a1, a2, a3, v0);
                    acc8(a0, a1, a2, a3, v1);
                    acc8(a0, a1, a2, a3, v2);
                    acc8(a0, a1, a2, a3, v3);
                    v0 = u0; v1 = u1; v2 = u2; v3 = u3;
                }
                acc8(a0, a1, a2, a3, v0);
                acc8(a0, a1, a2, a3, v1);
                acc8(a0, a1, a2, a3, v2);
                acc8(a0, a1, a2, a3, v3);
            }
            const int r = cnt - nfull;
            uint4 t0, t1, t2;
            if (r > 0) t0 = nfv[(size_t)srt[beg + nfull + 0] * 16 + sl];
            if (r > 1) t1 = nfv[(size_t)srt[beg + nfull + 1] * 16 + sl];
            if (r > 2) t2 = nfv[(size_t)srt[beg + nfull + 2] * 16 + sl];
            if (r > 0) acc8(a0, a1, a2, a3, t0);
            if (r > 1) acc8(a0, a1, a2, a3, t1);
            if (r > 2) acc8(a0, a1, a2, a3, t2);
        }
    }
    #pragma unroll
    for (int i = 0; i < 2; ++i) {
        const int n = w * 8 + i * 4 + qq;
        f32x2* A = i ? A1 : A0;
        uint4 o;                                   // all 64 lanes: 4 rows/wave
        o.x = (unsigned)f2bf(A[0].x) | ((unsigned)f2bf(A[0].y) << 16);
        o.y = (unsigned)f2bf(A[1].x) | ((unsigned)f2bf(A[1].y) << 16);
        o.z = (unsigned)f2bf(A[2].x) | ((unsigned)f2bf(A[2].y) << 16);
        o.w = (unsigned)f2bf(A[3].x) | ((unsigned)f2bf(A[3].y) << 16);
        *(uint4*)(tile + n * (AROWU / 2) + sl * 4) = o;
    }
    __syncthreads();

    // --- Phase C: 8 tiles x 8 col-chunks = 64 MFMA tasks over 16 waves
    const int m = lane & 15, q = lane >> 4;
    const ushort* lds = (const ushort*)tile;
    #pragma unroll
    for (int i = 0; i < 4; ++i) {
        const int task = w + 16 * i;                // 0..63, bijective
        const int t16  = task >> 3;                 // row-tile 0..7
        const int c0   = (task & 7) * 16;           // col chunk
        const int grow0 = b * BS + t16 * 16;
        if (grow0 < NN) {                           // last bucket: 5 full tiles
            bf16x8 a[4];
            const ushort* arow = lds + (t16 * 16 + m) * AROWU + q * 8;
            #pragma unroll
            for (int kk = 0; kk < 4; ++kk)
                a[kk] = *(const bf16x8*)(arow + kk * 32);
            float bv = bias[c0 + m];
            f32x4 acc = { bv, bv, bv, bv };
            const ushort* wrow = Wh + (size_t)(c0 + m) * D + q * 8;
            #pragma unroll
            for (int kk = 0; kk < 4; ++kk) {
                bf16x8 bb = *(const bf16x8*)(wrow + kk * 32);
                acc = __builtin_amdgcn_mfma_f32_16x16x32_bf16(a[kk], bb, acc, 0, 0, 0);
            }
            float* op = out + (size_t)(grow0 + q * 4) * D + c0 + m;
            op[0]     = acc[0];
            op[D]     = acc[1];
            op[2 * D] = acc[2];
            op[3 * D] = acc[3];
        }
    }
}

extern "C" void kernel_launch(void* const* d_in, const int* in_sizes, int n_in,
                              void* d_out, int out_size, void* d_ws, size_t ws_size,
                              hipStream_t stream) {
    const float* nf = (const float*)d_in[0];
    const int*   ei = (const int*)d_in[1];
    const float* W  = (const float*)d_in[2];
    const float* b  = (const float*)d_in[3];
    float* out = (float*)d_out;

    // workspace (~16.2 MB)
    ushort*   nfh  = (ushort*)d_ws;                    // NN*D bf16 = 12.8 MB
    ushort*   Wh   = nfh + (size_t)NN * D;             // 32 KB
    unsigned* buf  = (unsigned*)(Wh + D * D);          // NSB*EPB u32 = 3.2 MB
    ushort*   offs = (ushort*)(buf + (size_t)NSB * EPB); // (NB+1)*NSB = 154 KB

    k_prep_bucket<<<GRID_A, 512, 0, stream>>>(nf, W, ei, nfh, Wh, offs, buf);
    k_sort_agg   <<<NB, 1024, 0, stream>>>((const unsigned*)nfh, buf, offs, Wh, b, out);
}

// Round 4
// 136.345 us; speedup vs baseline: 1.0460x; 1.0460x over previous
//
#include <hip/hip_runtime.h>

// GNN layer: out = segment_sum(nf[src], dst) @ W.T + b
// N=50000, E=800000, D=128.
// R17: depth over occupancy. R16 post-mortem: FETCH ~78MB is ALREADY at the
// per-XCD compulsory bound (8 private L2s x ~43K unique rows x 256B ~= 88MB)
// -> locality schemes can't win; and WRITE 28->65MB at VGPR_Count=32 proved
// the launch_bounds(1024,8) 64-VGPR cap spills/sinks any pipeline (R15/R16
// both defeated by it). Gather is outstanding-miss bound: 78MB/48.5us =
// 1.6TB/s miss path = ~7 lines in flight per CU. Fix: launch_bounds(1024,4)
// (128 VGPR budget, 16 waves/CU) + Phase B dual-stream rotated pipeline:
// each quarter owns TWO consecutive nodes, walks both lists in lockstep,
// issues batch k+1's 8 dwordx4 (8KB/wave in flight) before accumulating
// batch k; srt indices prefetched one batch ahead; both tails merged into
// one up-front latency window. Producer + A-phases + MFMA Phase C = R15.

constexpr int NN = 50000;
constexpr int NE = 800000;
constexpr int D  = 128;

constexpr int BS   = 128;                      // nodes per bucket
constexpr int NB   = (NN + BS - 1) / BS;       // 391 buckets
constexpr int EPB  = 4096;                     // edges per producer block
constexpr int NSB  = (NE + EPB - 1) / EPB;     // 196 producer blocks
constexpr int CAP  = 4096;                     // per-bucket edge cap

constexpr int AROWU = 136;                     // tile row stride (ushorts)

typedef __attribute__((ext_vector_type(8))) short bf16x8;
typedef __attribute__((ext_vector_type(4))) float f32x4;
typedef __attribute__((ext_vector_type(2))) float f32x2;

__device__ inline unsigned short f2bf(float f) {           // RNE
    unsigned u = __float_as_uint(f);
    return (unsigned short)((u + 0x7fffu + ((u >> 16) & 1u)) >> 16);
}
__device__ inline float bflo(unsigned v) { return __uint_as_float(v << 16); }
__device__ inline float bfhi(unsigned v) { return __uint_as_float(v & 0xffff0000u); }

__device__ inline int wscan(int v) {           // wave-inclusive scan (64)
    #pragma unroll
    for (int o = 1; o < 64; o <<= 1) {
        int u = __shfl_up(v, o);
        if ((int)(threadIdx.x & 63) >= o) v += u;
    }
    return v;
}

__device__ inline void acc8(f32x2& a0, f32x2& a1, f32x2& a2, f32x2& a3, uint4 v) {
    a0 += (f32x2){bflo(v.x), bfhi(v.x)};
    a1 += (f32x2){bflo(v.y), bfhi(v.y)};
    a2 += (f32x2){bflo(v.z), bfhi(v.z)};
    a3 += (f32x2){bflo(v.w), bfhi(v.w)};
}

// ---- 1. fused prep (bf16 cvt) + bucket-sort partition ---------------------
constexpr int NF4 = NN * D / 4;                           // 1,600,000
constexpr int W4  = D * D / 4;                            // 4,096
constexpr int NBLK_P = (NF4 + W4 + 511) / 512;            // 3134
constexpr int GRID_A = NSB + NBLK_P;

__global__ __launch_bounds__(512) void k_prep_bucket(
    const float* __restrict__ nf, const float* __restrict__ W,
    const int* __restrict__ ei,
    ushort* __restrict__ nfh, ushort* __restrict__ Wh,
    ushort* __restrict__ offs, unsigned* __restrict__ buf)
{
    __shared__ int hist[NB], cur[NB];              // 3128 B
    __shared__ int wsum[8];
    __shared__ unsigned spk[EPB];                  // 16384 B
    const int t = threadIdx.x, lane = t & 63, w = t >> 6;

    if (blockIdx.x < NSB) {
        const int blk = blockIdx.x;
        const int e0  = blk * EPB;
        int cnt = NE - e0; if (cnt > EPB) cnt = EPB;

        for (int i = t; i < NB; i += 512) hist[i] = 0;
        __syncthreads();

        unsigned pk[8];
        #pragma unroll
        for (int j = 0; j < 8; ++j) {
            int idx = j * 512 + t;
            if (idx < cnt) {
                int e = e0 + idx;
                unsigned s = (unsigned)ei[e];
                unsigned d = (unsigned)ei[NE + e];
                pk[j] = (d << 16) | s;             // bucket = pk >> 23
                atomicAdd(&hist[pk[j] >> 23], 1);
            }
        }
        __syncthreads();
        // wave shfl scan over 391 (waves 0..6 carry data, wave 7 zeros)
        int h = (t < NB) ? hist[t] : 0;
        int v = wscan(h);
        if (lane == 63) wsum[w] = v;
        __syncthreads();
        int addv = 0;
        #pragma unroll
        for (int i = 0; i < 8; ++i) addv += (i < w) ? wsum[i] : 0;
        v += addv;
        if (t < NB) {
            int ex = v - h;                        // exclusive base
            cur[t] = ex;
            offs[t * NSB + blk] = (ushort)ex;      // TRANSPOSED: bucket-major
        }
        if (t == 0) offs[NB * NSB + blk] = (ushort)cnt;
        __syncthreads();
        #pragma unroll
        for (int j = 0; j < 8; ++j) {
            int idx = j * 512 + t;
            if (idx < cnt) {
                int l = atomicAdd(&cur[pk[j] >> 23], 1);
                spk[l] = pk[j];
            }
        }
        __syncthreads();
        for (int i = t; i < cnt; i += 512)         // dense coalesced 16KB
            buf[(size_t)blk * EPB + i] = spk[i];
    } else {
        // prep branch: bf16 conversion
        int i = (blockIdx.x - NSB) * 512 + t;
        if (i < NF4) {
            float4 v = ((const float4*)nf)[i];
            ((ushort4*)nfh)[i] = make_ushort4(f2bf(v.x), f2bf(v.y), f2bf(v.z), f2bf(v.w));
        } else if (i < NF4 + W4) {
            int k = i - NF4;
            float4 v = ((const float4*)W)[k];
            ((ushort4*)Wh)[k] = make_ushort4(f2bf(v.x), f2bf(v.y), f2bf(v.z), f2bf(v.w));
        }
    }
}

// ---- 2. fused gather-sort + aggregate + linear ----------------------------
__global__ __launch_bounds__(1024, 4) void k_sort_agg(
    const unsigned* __restrict__ nfh, const unsigned* __restrict__ buf,
    const ushort* __restrict__ offs, const ushort* __restrict__ Wh,
    const float* __restrict__ bias, float* __restrict__ out)
{
    __shared__ ushort srt[CAP];                     // 8192 B
    __shared__ int scnt[256];                       // 1024 B
    __shared__ int sbase[NSB], rbase[NSB];          // 1568 B
    __shared__ int hist[BS], off[BS], cur[BS];      // 1536 B
    __shared__ int wred[16];
    __shared__ __align__(16) unsigned tile[BS * AROWU / 2];  // 34816 B (~47.5KB)
    const int b = blockIdx.x, t = threadIdx.x;
    const int lane = t & 63, w = t >> 6;

    // --- Phase A1: per-producer run bases/counts -> wave shfl scan (1 barrier)
    int my = 0;
    if (t < NSB) {
        int o0 = (int)offs[b * NSB + t];           // coalesced 392B row
        int o1 = (int)offs[(b + 1) * NSB + t];
        rbase[t] = o0;
        my = o1 - o0;
    }
    if (t < BS) hist[t] = 0;
    int vs = 0;
    if (w < 4) {
        vs = wscan(my);
        if (lane == 63) wred[w] = vs;
    }
    __syncthreads();
    if (w < 4) {
        int addv = 0;
        #pragma unroll
        for (int i = 0; i < 3; ++i) addv += (i < w) ? wred[i] : 0;
        vs += addv;
        scnt[t] = vs;                              // global inclusive
        if (t < NSB) sbase[t] = vs - my;
    }
    __syncthreads();
    int total = scnt[NSB - 1];
    if (total > CAP) total = CAP;                  // defensive

    // --- Phase A2: load pk into REGISTERS + node histogram (no pkbuf)
    unsigned mypk[4];
    int mycnt = 0;
    #pragma unroll
    for (int j = 0; j < 4; ++j) {
        int p = t + j * 1024;
        if (p < total) {
            int lo = 0, hi = NSB - 1;              // min i: scnt[i] > p
            while (lo < hi) {
                int mid = (lo + hi) >> 1;
                if (scnt[mid] > p) hi = mid; else lo = mid + 1;
            }
            unsigned pk = buf[(size_t)lo * EPB + rbase[lo] + (p - sbase[lo])];
            mypk[j] = pk;
            atomicAdd(&hist[(pk >> 16) & (BS - 1)], 1);
            mycnt = j + 1;
        }
    }
    __syncthreads();

    // --- Phase A3: node wave-scan (2 barriers) + scatter into srt (local CSR)
    int hv = (t < BS) ? hist[t] : 0;
    int nv = 0;
    if (w < 2) {
        nv = wscan(hv);
        if (lane == 63) wred[8 + w] = nv;
    }
    __syncthreads();
    if (t < BS) {
        int ex = nv + ((w == 1) ? wred[8] : 0) - hv;
        off[t] = ex; cur[t] = ex;
    }
    __syncthreads();
    #pragma unroll
    for (int j = 0; j < 4; ++j) {
        if (j < mycnt) {
            unsigned pk = mypk[j];
            int n = (pk >> 16) & (BS - 1);
            int p = atomicAdd(&cur[n], 1);
            srt[p] = (ushort)(pk & 0xffffu);
        }
    }
    __syncthreads();

    // --- Phase B: dual-stream rotated pipeline.
    // Quarter qq owns nodes n0 = w*8+2*qq and n1 = n0+1 (consecutive CSR bins).
    // Per iteration: issue batch k+1's 8 dwordx4 (both streams) BEFORE
    // accumulating batch k; srt indices fetched one batch ahead.
    const int qq = lane >> 4;
    const int sl = lane & 15;
    const uint4* nfv = (const uint4*)nfh;          // row = idx*16 uint4s

    const int n0 = w * 8 + 2 * qq;
    const int n1 = n0 + 1;
    const int beg0 = off[n0], cnt0 = hist[n0];
    const int beg1 = off[n1], cnt1 = hist[n1];

    f32x2 A0[4] = {{0.f,0.f},{0.f,0.f},{0.f,0.f},{0.f,0.f}};
    f32x2 A1[4] = {{0.f,0.f},{0.f,0.f},{0.f,0.f},{0.f,0.f}};

    // ---- tails (cnt&3) first: both streams issued in ONE latency window
    const int f0 = cnt0 & ~3, r0 = cnt0 - f0;
    const int f1 = cnt1 & ~3, r1 = cnt1 - f1;
    {
        uint4 t00, t01, t02, t10, t11, t12;
        if (r0 > 0) t00 = nfv[(size_t)srt[beg0 + f0 + 0] * 16 + sl];
        if (r0 > 1) t01 = nfv[(size_t)srt[beg0 + f0 + 1] * 16 + sl];
        if (r0 > 2) t02 = nfv[(size_t)srt[beg0 + f0 + 2] * 16 + sl];
        if (r1 > 0) t10 = nfv[(size_t)srt[beg1 + f1 + 0] * 16 + sl];
        if (r1 > 1) t11 = nfv[(size_t)srt[beg1 + f1 + 1] * 16 + sl];
        if (r1 > 2) t12 = nfv[(size_t)srt[beg1 + f1 + 2] * 16 + sl];
        if (r0 > 0) acc8(A0[0], A0[1], A0[2], A0[3], t00);
        if (r0 > 1) acc8(A0[0], A0[1], A0[2], A0[3], t01);
        if (r0 > 2) acc8(A0[0], A0[1], A0[2], A0[3], t02);
        if (r1 > 0) acc8(A1[0], A1[1], A1[2], A1[3], t10);
        if (r1 > 1) acc8(A1[0], A1[1], A1[2], A1[3], t11);
        if (r1 > 2) acc8(A1[0], A1[1], A1[2], A1[3], t12);
    }

    // ---- full batches, dual-stream depth-2 rotation
    const int nb0 = f0 >> 2, nb1 = f1 >> 2;
    int nbm = nb0 > nb1 ? nb0 : nb1;               // wave-uniform trip count
    {
        int o16 = __shfl_xor(nbm, 16); nbm = nbm > o16 ? nbm : o16;
        int o32 = __shfl_xor(nbm, 32); nbm = nbm > o32 ? nbm : o32;
    }
    int i00, i01, i02, i03, i10, i11, i12, i13;    // idx of in-flight batch+1
    uint4 V00, V01, V02, V03, V10, V11, V12, V13;  // in-flight batch data
    if (nb0 > 0) {
        i00 = srt[beg0 + 0]; i01 = srt[beg0 + 1];
        i02 = srt[beg0 + 2]; i03 = srt[beg0 + 3];
        V00 = nfv[(size_t)i00 * 16 + sl]; V01 = nfv[(size_t)i01 * 16 + sl];
        V02 = nfv[(size_t)i02 * 16 + sl]; V03 = nfv[(size_t)i03 * 16 + sl];
    }
    if (nb1 > 0) {
        i10 = srt[beg1 + 0]; i11 = srt[beg1 + 1];
        i12 = srt[beg1 + 2]; i13 = srt[beg1 + 3];
        V10 = nfv[(size_t)i10 * 16 + sl]; V11 = nfv[(size_t)i11 * 16 + sl];
        V12 = nfv[(size_t)i12 * 16 + sl]; V13 = nfv[(size_t)i13 * 16 + sl];
    }
    for (int k = 0; k < nbm; ++k) {
        const bool g0 = (k + 1 < nb0), g1 = (k + 1 < nb1);
        // fetch next batch's indices (LDS; hides under the accs below)
        if (g0) {
            const int p = beg0 + (k + 1) * 4;
            i00 = srt[p]; i01 = srt[p + 1]; i02 = srt[p + 2]; i03 = srt[p + 3];
        }
        if (g1) {
            const int p = beg1 + (k + 1) * 4;
            i10 = srt[p]; i11 = srt[p + 1]; i12 = srt[p + 2]; i13 = srt[p + 3];
        }
        // issue next batch's global loads
        uint4 U00, U01, U02, U03, U10, U11, U12, U13;
        if (g0) {
            U00 = nfv[(size_t)i00 * 16 + sl]; U01 = nfv[(size_t)i01 * 16 + sl];
            U02 = nfv[(size_t)i02 * 16 + sl]; U03 = nfv[(size_t)i03 * 16 + sl];
        }
        if (g1) {
            U10 = nfv[(size_t)i10 * 16 + sl]; U11 = nfv[(size_t)i11 * 16 + sl];
            U12 = nfv[(size_t)i12 * 16 + sl]; U13 = nfv[(size_t)i13 * 16 + sl];
        }
        // drain current batch
        if (k < nb0) {
            acc8(A0[0], A0[1], A0[2], A0[3], V00);
            acc8(A0[0], A0[1], A0[2], A0[3], V01);
            acc8(A0[0], A0[1], A0[2], A0[3], V02);
            acc8(A0[0], A0[1], A0[2], A0[3], V03);
        }
        if (k < nb1) {
            acc8(A1[0], A1[1], A1[2], A1[3], V10);
            acc8(A1[0], A1[1], A1[2], A1[3], V11);
            acc8(A1[0], A1[1], A1[2], A1[3], V12);
            acc8(A1[0], A1[1], A1[2], A1[3], V13);
        }
        if (g0) { V00 = U00; V01 = U01; V02 = U02; V03 = U03; }
        if (g1) { V10 = U10; V11 = U11; V12 = U12; V13 = U13; }
    }

    // ---- write both tile rows (all 64 lanes: 8 rows/wave)
    {
        uint4 o;
        o.x = (unsigned)f2bf(A0[0].x) | ((unsigned)f2bf(A0[0].y) << 16);
        o.y = (unsigned)f2bf(A0[1].x) | ((unsigned)f2bf(A0[1].y) << 16);
        o.z = (unsigned)f2bf(A0[2].x) | ((unsigned)f2bf(A0[2].y) << 16);
        o.w = (unsigned)f2bf(A0[3].x) | ((unsigned)f2bf(A0[3].y) << 16);
        *(uint4*)(tile + n0 * (AROWU / 2) + sl * 4) = o;
        o.x = (unsigned)f2bf(A1[0].x) | ((unsigned)f2bf(A1[0].y) << 16);
        o.y = (unsigned)f2bf(A1[1].x) | ((unsigned)f2bf(A1[1].y) << 16);
        o.z = (unsigned)f2bf(A1[2].x) | ((unsigned)f2bf(A1[2].y) << 16);
        o.w = (unsigned)f2bf(A1[3].x) | ((unsigned)f2bf(A1[3].y) << 16);
        *(uint4*)(tile + n1 * (AROWU / 2) + sl * 4) = o;
    }
    __syncthreads();

    // --- Phase C: 8 tiles x 8 col-chunks = 64 MFMA tasks over 16 waves
    const int m = lane & 15, q = lane >> 4;
    const ushort* lds = (const ushort*)tile;
    #pragma unroll
    for (int i = 0; i < 4; ++i) {
        const int task = w + 16 * i;                // 0..63, bijective
        const int t16  = task >> 3;                 // row-tile 0..7
        const int c0   = (task & 7) * 16;           // col chunk
        const int grow0 = b * BS + t16 * 16;
        if (grow0 < NN) {                           // last bucket: 5 full tiles
            bf16x8 a[4];
            const ushort* arow = lds + (t16 * 16 + m) * AROWU + q * 8;
            #pragma unroll
            for (int kk = 0; kk < 4; ++kk)
                a[kk] = *(const bf16x8*)(arow + kk * 32);
            float bv = bias[c0 + m];
            f32x4 acc = { bv, bv, bv, bv };
            const ushort* wrow = Wh + (size_t)(c0 + m) * D + q * 8;
            #pragma unroll
            for (int kk = 0; kk < 4; ++kk) {
                bf16x8 bb = *(const bf16x8*)(wrow + kk * 32);
                acc = __builtin_amdgcn_mfma_f32_16x16x32_bf16(a[kk], bb, acc, 0, 0, 0);
            }
            float* op = out + (size_t)(grow0 + q * 4) * D + c0 + m;
            op[0]     = acc[0];
            op[D]     = acc[1];
            op[2 * D] = acc[2];
            op[3 * D] = acc[3];
        }
    }
}

extern "C" void kernel_launch(void* const* d_in, const int* in_sizes, int n_in,
                              void* d_out, int out_size, void* d_ws, size_t ws_size,
                              hipStream_t stream) {
    const float* nf = (const float*)d_in[0];
    const int*   ei = (const int*)d_in[1];
    const float* W  = (const float*)d_in[2];
    const float* b  = (const float*)d_in[3];
    float* out = (float*)d_out;

    // workspace (~16.2 MB)
    ushort*   nfh  = (ushort*)d_ws;                    // NN*D bf16 = 12.8 MB
    ushort*   Wh   = nfh + (size_t)NN * D;             // 32 KB
    unsigned* buf  = (unsigned*)(Wh + D * D);          // NSB*EPB u32 = 3.2 MB
    ushort*   offs = (ushort*)(buf + (size_t)NSB * EPB); // (NB+1)*NSB = 154 KB

    k_prep_bucket<<<GRID_A, 512, 0, stream>>>(nf, W, ei, nfh, Wh, offs, buf);
    k_sort_agg   <<<NB, 1024, 0, stream>>>((const unsigned*)nfh, buf, offs, Wh, b, out);
}